// Round 9
// baseline (831.681 us; speedup 1.0000x reference)
//
#include <hip/hip_runtime.h>
#include <math.h>

// Problem constants (fixed by setup_inputs)
static constexpr int BATCH = 32;
static constexpr int NPRED = 512;   // outputs rows (LAP columns)
static constexpr int NTGT  = 200;   // targets rows (LAP rows)
static constexpr int DIM   = 768;
static constexpr int MTILES = 7;    // 32-row m-tiles per batch (7*32 >= 200)
static constexpr int NTILES = 4;    // 128-col n-tiles per batch
static constexpr int TOTAL_TILES = MTILES * NTILES * BATCH;  // 896
static constexpr int GEMM_BLOCKS = 224;   // + 32 LAP blocks = 256 = #CUs
#define BIGF 1e9f                   // fresh-minv init (matches reference BIG)
#define INFF __builtin_inff()       // 'used' sentinel: INF - delta == INF (exact)

// ---------------------------------------------------------------------------
// Row squared-norms: one wave per row
// ---------------------------------------------------------------------------
__global__ __launch_bounds__(64) void row_norms_kernel(const float* __restrict__ x,
                                                       float* __restrict__ out) {
    int row = blockIdx.x;
    const float4* r = (const float4*)(x + (size_t)row * DIM);
    float s = 0.f;
#pragma unroll
    for (int k = 0; k < 3; ++k) {
        float4 v = r[threadIdx.x + 64 * k];
        s += v.x * v.x + v.y * v.y + v.z * v.z + v.w * v.w;
    }
#pragma unroll
    for (int off = 32; off; off >>= 1) s += __shfl_down(s, off);
    if (threadIdx.x == 0) out[row] = s;
}

// ---------------------------------------------------------------------------
// LAP helpers
// ---------------------------------------------------------------------------
__device__ __forceinline__ int rl(int v, int l) {
    return __builtin_amdgcn_readlane(v, l);
}
__device__ __forceinline__ float rlf(float v, int l) {
    return __int_as_float(__builtin_amdgcn_readlane(__float_as_int(v), l));
}
__device__ __forceinline__ int sel8i(const int* a, int s) {
    int r = a[0];
#pragma unroll
    for (int k = 1; k < 8; ++k) r = (s == k) ? a[k] : r;
    return r;
}
__device__ __forceinline__ float sel8f(const float* a, int s) {
    float r = a[0];
#pragma unroll
    for (int k = 1; k < 8; ++k) r = (s == k) ? a[k] : r;
    return r;
}
// Wave-wide min via DPP (VALU-only): lane 63 ends with min of all 64 lanes.
__device__ __forceinline__ float dpp_min_f32(float x) {
    float t;
    t = __int_as_float(__builtin_amdgcn_update_dpp(__float_as_int(x), __float_as_int(x), 0x111, 0xF, 0xF, false)); x = fminf(x, t);
    t = __int_as_float(__builtin_amdgcn_update_dpp(__float_as_int(x), __float_as_int(x), 0x112, 0xF, 0xF, false)); x = fminf(x, t);
    t = __int_as_float(__builtin_amdgcn_update_dpp(__float_as_int(x), __float_as_int(x), 0x114, 0xF, 0xF, false)); x = fminf(x, t);
    t = __int_as_float(__builtin_amdgcn_update_dpp(__float_as_int(x), __float_as_int(x), 0x118, 0xF, 0xF, false)); x = fminf(x, t);
    t = __int_as_float(__builtin_amdgcn_update_dpp(__float_as_int(x), __float_as_int(x), 0x142, 0xF, 0xF, false)); x = fminf(x, t);
    t = __int_as_float(__builtin_amdgcn_update_dpp(__float_as_int(x), __float_as_int(x), 0x143, 0xF, 0xF, false)); x = fminf(x, t);
    return x;
}
// Lane-local argmin tree over 8 values (tie -> lower q).
__device__ __forceinline__ float tree8(const float* m, int& lq) {
    float v01 = (m[0] <= m[1]) ? m[0] : m[1];
    int   q01 = (m[0] <= m[1]) ? 0 : 1;
    float v23 = (m[2] <= m[3]) ? m[2] : m[3];
    int   q23 = (m[2] <= m[3]) ? 2 : 3;
    float v45 = (m[4] <= m[5]) ? m[4] : m[5];
    int   q45 = (m[4] <= m[5]) ? 4 : 5;
    float v67 = (m[6] <= m[7]) ? m[6] : m[7];
    int   q67 = (m[6] <= m[7]) ? 6 : 7;
    float v03 = (v01 <= v23) ? v01 : v23;
    int   q03 = (v01 <= v23) ? q01 : q23;
    float v47 = (v45 <= v67) ? v45 : v67;
    int   q47 = (v45 <= v67) ? q45 : q67;
    lq = (v03 <= v47) ? q03 : q47;
    return (v03 <= v47) ? v03 : v47;
}

// ---------------------------------------------------------------------------
// FUSED kernel, 256 blocks = 1 per CU (so GEMM and LAP blocks don't share
// VALU issue slots -- r6's failure mode). Blocks [0,224): persistent GEMM,
// 4 tiles each, mtile-major order (all batches' mtile-0 assigned in round 1
// -> LAP initial stall ~1 tile-time). Blocks [224,256): LAP, ONE WAVE (waves
// 1-3 exit immediately; zero barriers in the LAP path -- single-wave LDS is
// in-order). Flags: per-(batch,mtile) release/acquire counters (r6-verified).
// GEMM blocks never wait -> deadlock-free for any placement. LAP inner loop
// is byte-identical to round 8's verified bit-exact 600us loop.
// ---------------------------------------------------------------------------
__global__ __launch_bounds__(256) void fused_kernel(const float* __restrict__ O,
                                                    const float* __restrict__ T,
                                                    const float* __restrict__ no_arr,
                                                    const float* __restrict__ nt_arr,
                                                    float* __restrict__ cost,
                                                    int* __restrict__ flags,
                                                    int* __restrict__ out) {
    if (blockIdx.x < GEMM_BLOCKS) {
        // ------------- persistent cost producer: 32x128 tiles -------------
        __shared__ float As[32][33];   // [k][m], +1 pad
        __shared__ float Bs[32][129];  // [k][n], +1 pad
        const int tid = threadIdx.x;
        const int tx = tid & 31;   // n
        const int ty = tid >> 5;   // m

        for (int t = blockIdx.x; t < TOTAL_TILES; t += GEMM_BLOCKS) {
            const int mt = t >> 7;          // mtile-major: 128 tiles per layer
            const int rm = t & 127;
            const int b  = rm >> 2;
            const int m0 = mt * 32;
            const int n0 = (rm & 3) * 128;
            const float* Tb = T + (size_t)b * NTGT * DIM;
            const float* Ob = O + (size_t)b * NPRED * DIM;

            float acc[4][4] = {};

            for (int k0 = 0; k0 < DIM; k0 += 32) {
                {
                    int ar = tid >> 3;
                    int ak = (tid & 7) << 2;
                    int gm = m0 + ar; if (gm > NTGT - 1) gm = NTGT - 1;
                    float4 vA = *(const float4*)(Tb + (size_t)gm * DIM + k0 + ak);
                    As[ak + 0][ar] = vA.x; As[ak + 1][ar] = vA.y;
                    As[ak + 2][ar] = vA.z; As[ak + 3][ar] = vA.w;
                }
#pragma unroll
                for (int q = 0; q < 4; ++q) {
                    int idx = q * 256 + tid;
                    int br = idx >> 3;
                    int bk = (idx & 7) << 2;
                    float4 vB = *(const float4*)(Ob + (size_t)(n0 + br) * DIM + k0 + bk);
                    Bs[bk + 0][br] = vB.x; Bs[bk + 1][br] = vB.y;
                    Bs[bk + 2][br] = vB.z; Bs[bk + 3][br] = vB.w;
                }
                __syncthreads();
#pragma unroll
                for (int k = 0; k < 32; ++k) {
                    float a0 = As[k][ty], a1 = As[k][ty + 8],
                          a2 = As[k][ty + 16], a3 = As[k][ty + 24];
                    float b0 = Bs[k][tx],      b1 = Bs[k][tx + 32],
                          b2 = Bs[k][tx + 64], b3 = Bs[k][tx + 96];
                    acc[0][0] += a0 * b0; acc[0][1] += a0 * b1; acc[0][2] += a0 * b2; acc[0][3] += a0 * b3;
                    acc[1][0] += a1 * b0; acc[1][1] += a1 * b1; acc[1][2] += a1 * b2; acc[1][3] += a1 * b3;
                    acc[2][0] += a2 * b0; acc[2][1] += a2 * b1; acc[2][2] += a2 * b2; acc[2][3] += a2 * b3;
                    acc[3][0] += a3 * b0; acc[3][1] += a3 * b1; acc[3][2] += a3 * b2; acc[3][3] += a3 * b3;
                }
                __syncthreads();
            }

#pragma unroll
            for (int i = 0; i < 4; ++i) {
                int gm = m0 + ty + 8 * i;
                if (gm < NTGT) {
                    float ntv = nt_arr[b * NTGT + gm];
#pragma unroll
                    for (int j = 0; j < 4; ++j) {
                        int gn = n0 + tx + 32 * j;
                        float d2 = ntv + no_arr[b * NPRED + gn] - 2.0f * acc[i][j];
                        cost[((size_t)b * NTGT + gm) * NPRED + gn] = sqrtf(fmaxf(d2, 0.0f));
                    }
                }
            }

            __threadfence();      // make this thread's stores device-visible
            __syncthreads();      // all threads' stores fenced before publish
            if (tid == 0)
                __hip_atomic_fetch_add(&flags[b * MTILES + mt], 1,
                                       __ATOMIC_RELEASE, __HIP_MEMORY_SCOPE_AGENT);
            __syncthreads();      // keep waves together before LDS reuse
        }
        return;
    }

    // --------------------------- LAP consumer ---------------------------
    if (threadIdx.x >= 64) return;        // single wave; AMD barrier-free path
    const int b = blockIdx.x - GEMM_BLOCKS;
    const int lane = threadIdx.x;
    const float* C = cost + (size_t)b * NTGT * NPRED;
    const float* Cl = C + lane * 8;       // lane's 8-column slice base

    __shared__ float u0[NTGT + 1];        // row duals (stable during a row-step)
    __shared__ int g2p[NTGT];

    for (int k = lane; k < NTGT + 1; k += 64) u0[k] = 0.f;

    float v[8], minv[8], up[8];
    int p_arr[8], way_arr[8];
#pragma unroll
    for (int q = 0; q < 8; ++q) {
        v[q] = 0.f; up[q] = 0.f; p_arr[q] = 0; way_arr[q] = 0;
    }

    int waited = -1;
    auto wait_tile = [&](int t) {
        if (t > waited) {
            while (__hip_atomic_load(&flags[b * MTILES + t],
                                     __ATOMIC_ACQUIRE, __HIP_MEMORY_SCOPE_AGENT) < NTILES)
                __builtin_amdgcn_s_sleep(2);
            waited = t;
        }
    };

    wait_tile(0);
    float4 ca = *(const float4*)(Cl);         // prefetch row 0 (row-step i=1)
    float4 cb = *(const float4*)(Cl + 4);
    float4 sa = ca, sb = cb;                  // speculative shadow regs

    for (int i = 1; i <= NTGT; ++i) {
#pragma unroll
        for (int q = 0; q < 8; ++q) minv[q] = BIGF;
        float uI = 0.f;       // u[i] accumulator (virtual col 0), uniform
        float u_i0 = 0.f;     // u of current scan row (row i starts at 0)
        int j0 = 0;
        int j1 = 0;
        int spec_j = 0;       // predicted next winner column (1-based)

        for (int it = 0; it <= NPRED; ++it) {
            float c[8];
            c[0] = ca.x; c[1] = ca.y; c[2] = ca.z; c[3] = ca.w;
            c[4] = cb.x; c[5] = cb.y; c[6] = cb.z; c[7] = cb.w;

            // scan row i0: reduced cost, same float order as reference
            bool used_b[8];
#pragma unroll
            for (int q = 0; q < 8; ++q) {
                float cur = (c[q] - u_i0) - v[q];
                used_b[q] = (minv[q] == INFF);
                float cure = used_b[q] ? INFF : cur;
                bool imp = cure < minv[q];
                minv[q] = imp ? cure : minv[q];
                way_arr[q] = imp ? j0 : way_arr[q];
            }

            // primary argmin (exact; tie -> lowest column)
            int lq;
            float lval = tree8(minv, lq);
            int   psel = sel8i(p_arr, lq);
            float usel = sel8f(up, lq);
            float wmin = rlf(dpp_min_f32(lval), 63);
            unsigned long long mask = __ballot(lval == wmin);
            int w = (int)__builtin_ctzll(mask);
            int qw  = rl(lq, w);
            int i0n = rl(psel, w);              // p[j1]
            float u_n = rlf(usel, w);           // u0[p[j1]] (start-of-row value)
            float delta = wmin;
            j1 = w * 8 + qw + 1;
            bool done = (i0n == 0);

            if (!done) {
                // demand / hit for the row we must scan next
                if (j1 == spec_j) {
                    ca = sa; cb = sb;           // shadow load already complete
                } else {
                    const float* Crow = Cl + (size_t)(i0n - 1) * NPRED;
                    ca = *(const float4*)(Crow);
                    cb = *(const float4*)(Crow + 4);
                }
                // cheap runner-up speculation for the NEXT iteration, issued
                // before the dual updates (maximum latency cover). Uniform
                // minv shift preserves ordering among old candidates.
                float lv2 = (lane == w) ? INFF : lval;
                float wm2 = rlf(dpp_min_f32(lv2), 63);
                unsigned long long m2 = __ballot(lv2 == wm2);
                int w2 = (int)__builtin_ctzll(m2);
                int q2 = rl(lq, w2);
                int p2 = rl(psel, w2);
                int sj = w2 * 8 + q2 + 1;
                if (p2 != 0 && sj != spec_j) {
                    const float* Srow = Cl + (size_t)(p2 - 1) * NPRED;
                    sa = *(const float4*)(Srow);
                    sb = *(const float4*)(Srow + 4);
                }
                spec_j = sj;   // if p2==0, a hit implies done (data unused)
            }

            // dual updates (reference order; j1 not yet marked used).
            // x +/- 0.0f is bit-exact; INF - delta == INF keeps used cols inert.
            uI += delta;
#pragma unroll
            for (int q = 0; q < 8; ++q) {
                float d0 = used_b[q] ? delta : 0.f;
                v[q]  -= d0;
                up[q] += d0;
                minv[q] -= delta;
            }
            // mark j1 used
            {
                bool lw = (lane == w);
#pragma unroll
                for (int q = 0; q < 8; ++q)
                    minv[q] = (lw && q == qw) ? INFF : minv[q];
            }

            if (done) break;
            u_i0 = u_n;
            j0 = j1;
        }

        // wait for + prefetch next row-step's first scan row (row i, 0-based)
        if (i < NTGT) {
            wait_tile(i >> 5);
            const float* Crow = Cl + (size_t)i * NPRED;
            ca = *(const float4*)(Crow);
            cb = *(const float4*)(Crow + 4);
        }

        // write back u (pre-augment p): used cols carry u0[p]+deltas in up[]
#pragma unroll
        for (int q = 0; q < 8; ++q) {
            bool usedq = (minv[q] == INFF);
            if (usedq && p_arr[q] != 0) u0[p_arr[q]] = up[q];
        }
        if (lane == 0) u0[i] = uI;

        // backtrack augmenting path (uniform scalar walk over registers)
        {
            int j = j1;
            for (int s = 0; s <= NPRED; ++s) {
                int ow = (j - 1) >> 3, oq = (j - 1) & 7;
                int wj = rl(sel8i(way_arr, oq), ow);    // way[j]
                int pOfW;
                if (wj == 0) {
                    pOfW = i;                           // p[0] = i (virtual)
                } else {
                    int ow2 = (wj - 1) >> 3, oq2 = (wj - 1) & 7;
                    pOfW = rl(sel8i(p_arr, oq2), ow2);  // old p[way[j]]
                }
#pragma unroll
                for (int q = 0; q < 8; ++q) {
                    bool mine = (lane == ow) && (q == oq);
                    p_arr[q] = mine ? pOfW : p_arr[q];
                }
                if (wj == 0) break;
                j = wj;
            }
        }

        // refresh up = u0[p[col]] with post-augment p (same wave: LDS in-order)
#pragma unroll
        for (int q = 0; q < 8; ++q) up[q] = u0[p_arr[q]];
    }

    // invert matching: g2p[row] = col (0-based pred index)
#pragma unroll
    for (int q = 0; q < 8; ++q) {
        int r = p_arr[q];
        if (r > 0) g2p[r - 1] = lane * 8 + q;
    }

    // sort by pred index via rank counting (values distinct)
    for (int t = lane; t < NTGT; t += 64) {
        int myv = g2p[t];
        int rank = 0;
        for (int l = 0; l < NTGT; ++l) rank += (g2p[l] < myv) ? 1 : 0;
        out[b * 2 * NTGT + rank] = myv;          // index_i: sorted pred indices
        out[b * 2 * NTGT + NTGT + rank] = t;     // index_j: gt index (argsort)
    }
}

extern "C" void kernel_launch(void* const* d_in, const int* in_sizes, int n_in,
                              void* d_out, int out_size, void* d_ws, size_t ws_size,
                              hipStream_t stream) {
    const float* outputs = (const float*)d_in[0];  // [32, 512, 768]
    const float* targets = (const float*)d_in[1];  // [32, 200, 768]
    int* out = (int*)d_out;                        // [32, 2, 200] int32

    float* cost   = (float*)d_ws;                         // [32][200][512]
    float* no_arr = cost + (size_t)BATCH * NTGT * NPRED;  // [32*512]
    float* nt_arr = no_arr + (size_t)BATCH * NPRED;       // [32*200]
    int*   flags  = (int*)(nt_arr + (size_t)BATCH * NTGT);// [32*7]

    hipMemsetAsync(flags, 0, BATCH * MTILES * sizeof(int), stream);
    row_norms_kernel<<<BATCH * NPRED, 64, 0, stream>>>(outputs, no_arr);
    row_norms_kernel<<<BATCH * NTGT, 64, 0, stream>>>(targets, nt_arr);
    fused_kernel<<<GEMM_BLOCKS + BATCH, 256, 0, stream>>>(
        outputs, targets, no_arr, nt_arr, cost, flags, out);
}

// Round 10
// 766.930 us; speedup vs baseline: 1.0844x; 1.0844x over previous
//
#include <hip/hip_runtime.h>
#include <math.h>

// Problem constants (fixed by setup_inputs)
static constexpr int BATCH = 32;
static constexpr int NPRED = 512;   // outputs rows (LAP columns)
static constexpr int NTGT  = 200;   // targets rows (LAP rows)
static constexpr int DIM   = 768;
#define BIGF 1e9f                   // fresh-minv init (matches reference BIG)
#define QNANF __int_as_float(0x7fc00000)  // 'used' sentinel: NaN
// NaN-sentinel invariants (all exact): cur < NaN == false; NaN - delta == NaN;
// fminf(x, NaN) == x (C99); ballot(lval==wmin) excludes NaN lanes.

// ---------------------------------------------------------------------------
// Row squared-norms for BOTH inputs in one launch (identical per-row code and
// reduction order as prior rounds -> identical bits).
// ---------------------------------------------------------------------------
__global__ __launch_bounds__(64) void norms_kernel(const float* __restrict__ O,
                                                   const float* __restrict__ T,
                                                   float* __restrict__ no_arr,
                                                   float* __restrict__ nt_arr) {
    int row = blockIdx.x;
    const float* src;
    float* dst;
    if (row < BATCH * NPRED) {
        src = O + (size_t)row * DIM;            dst = no_arr + row;
    } else {
        int r2 = row - BATCH * NPRED;
        src = T + (size_t)r2 * DIM;             dst = nt_arr + r2;
    }
    const float4* r = (const float4*)src;
    float s = 0.f;
#pragma unroll
    for (int k = 0; k < 3; ++k) {
        float4 v = r[threadIdx.x + 64 * k];
        s += v.x * v.x + v.y * v.y + v.z * v.z + v.w * v.w;
    }
#pragma unroll
    for (int off = 32; off; off >>= 1) s += __shfl_down(s, off);
    if (threadIdx.x == 0) *dst = s;
}

// ---------------------------------------------------------------------------
// cost[b][m][n] = sqrt(max(nt[m] + no[n] - 2 * dot(T[m], O[n]), 0))
// 128(m) x 64(n) tile, 256 threads, 8x4 acc/thread. [k][m]/[k][n] LDS with
// 16B-aligned strides (132 / 68): inner loop = 3x ds_read_b128 per 32 FMA.
// Summation: k-ascending single accumulator chain -> bit-identical cost to
// rounds 1-8 (verified absmax 0).
// ---------------------------------------------------------------------------
__global__ __launch_bounds__(256) void cost_kernel(const float* __restrict__ O,
                                                   const float* __restrict__ T,
                                                   const float* __restrict__ no_arr,
                                                   const float* __restrict__ nt_arr,
                                                   float* __restrict__ cost) {
    const int b  = blockIdx.z;
    const int m0 = blockIdx.y * 128;
    const int n0 = blockIdx.x * 64;
    const float* Tb = T + (size_t)b * NTGT * DIM;
    const float* Ob = O + (size_t)b * NPRED * DIM;

    __shared__ __align__(16) float As[32][132];  // [k][m], 132*4B = 33*16B
    __shared__ __align__(16) float Bs[32][68];   // [k][n], 68*4B = 17*16B

    const int tid = threadIdx.x;
    const int tx = tid & 15;   // n/4
    const int ty = tid >> 4;   // m/8

    float acc[8][4] = {};

    for (int k0 = 0; k0 < DIM; k0 += 32) {
        // A: 128 rows x 32 k = 1024 float4, 4/thread (clamped rows)
#pragma unroll
        for (int q = 0; q < 4; ++q) {
            int f = tid + q * 256;
            int r = f >> 3;             // 0..127
            int kk = (f & 7) << 2;
            int gm = m0 + r; if (gm > NTGT - 1) gm = NTGT - 1;
            float4 vA = *(const float4*)(Tb + (size_t)gm * DIM + k0 + kk);
            As[kk + 0][r] = vA.x; As[kk + 1][r] = vA.y;
            As[kk + 2][r] = vA.z; As[kk + 3][r] = vA.w;
        }
        // B: 64 rows x 32 k = 512 float4, 2/thread
#pragma unroll
        for (int q = 0; q < 2; ++q) {
            int f = tid + q * 256;
            int r = f >> 3;             // 0..63
            int kk = (f & 7) << 2;
            float4 vB = *(const float4*)(Ob + (size_t)(n0 + r) * DIM + k0 + kk);
            Bs[kk + 0][r] = vB.x; Bs[kk + 1][r] = vB.y;
            Bs[kk + 2][r] = vB.z; Bs[kk + 3][r] = vB.w;
        }
        __syncthreads();
#pragma unroll
        for (int k = 0; k < 32; ++k) {
            float4 a0 = *(const float4*)&As[k][ty * 8];
            float4 a1 = *(const float4*)&As[k][ty * 8 + 4];
            float4 bv = *(const float4*)&Bs[k][tx * 4];
            float av[8] = {a0.x, a0.y, a0.z, a0.w, a1.x, a1.y, a1.z, a1.w};
#pragma unroll
            for (int i = 0; i < 8; ++i) {
                acc[i][0] += av[i] * bv.x; acc[i][1] += av[i] * bv.y;
                acc[i][2] += av[i] * bv.z; acc[i][3] += av[i] * bv.w;
            }
        }
        __syncthreads();
    }

    {
        float4 nov = *(const float4*)(no_arr + b * NPRED + n0 + (tx << 2));
#pragma unroll
        for (int i = 0; i < 8; ++i) {
            int gm = m0 + ty * 8 + i;
            if (gm < NTGT) {
                float ntv = nt_arr[b * NTGT + gm];
                float4 o;
                o.x = sqrtf(fmaxf(ntv + nov.x - 2.0f * acc[i][0], 0.0f));
                o.y = sqrtf(fmaxf(ntv + nov.y - 2.0f * acc[i][1], 0.0f));
                o.z = sqrtf(fmaxf(ntv + nov.z - 2.0f * acc[i][2], 0.0f));
                o.w = sqrtf(fmaxf(ntv + nov.w - 2.0f * acc[i][3], 0.0f));
                *(float4*)&cost[((size_t)b * NTGT + gm) * NPRED + n0 + (tx << 2)] = o;
            }
        }
    }
}

// ---------------------------------------------------------------------------
// LAP helpers
// ---------------------------------------------------------------------------
__device__ __forceinline__ int rl(int v, int l) {
    return __builtin_amdgcn_readlane(v, l);
}
__device__ __forceinline__ float rlf(float v, int l) {
    return __int_as_float(__builtin_amdgcn_readlane(__float_as_int(v), l));
}
__device__ __forceinline__ int sel8i(const int* a, int s) {
    int r = a[0];
#pragma unroll
    for (int k = 1; k < 8; ++k) r = (s == k) ? a[k] : r;
    return r;
}
__device__ __forceinline__ float sel8f(const float* a, int s) {
    float r = a[0];
#pragma unroll
    for (int k = 1; k < 8; ++k) r = (s == k) ? a[k] : r;
    return r;
}
// Wave-wide min via DPP (VALU-only): lane 63 ends with min of all 64 lanes.
// fminf skips NaN (returns the number) -> used cols drop out naturally.
__device__ __forceinline__ float dpp_min_f32(float x) {
    float t;
    t = __int_as_float(__builtin_amdgcn_update_dpp(__float_as_int(x), __float_as_int(x), 0x111, 0xF, 0xF, false)); x = fminf(x, t);
    t = __int_as_float(__builtin_amdgcn_update_dpp(__float_as_int(x), __float_as_int(x), 0x112, 0xF, 0xF, false)); x = fminf(x, t);
    t = __int_as_float(__builtin_amdgcn_update_dpp(__float_as_int(x), __float_as_int(x), 0x114, 0xF, 0xF, false)); x = fminf(x, t);
    t = __int_as_float(__builtin_amdgcn_update_dpp(__float_as_int(x), __float_as_int(x), 0x118, 0xF, 0xF, false)); x = fminf(x, t);
    t = __int_as_float(__builtin_amdgcn_update_dpp(__float_as_int(x), __float_as_int(x), 0x142, 0xF, 0xF, false)); x = fminf(x, t);
    t = __int_as_float(__builtin_amdgcn_update_dpp(__float_as_int(x), __float_as_int(x), 0x143, 0xF, 0xF, false)); x = fminf(x, t);
    return x;
}
// NaN-safe lane-local argmin tree over 8 values (tie -> lower q; NaN loses).
// node: m = fminf(a,b); pick qa iff m==a (ties -> first; a==NaN -> false).
__device__ __forceinline__ float tree8n(const float* m, int& lq) {
    float v01 = fminf(m[0], m[1]); int q01 = (v01 == m[0]) ? 0 : 1;
    float v23 = fminf(m[2], m[3]); int q23 = (v23 == m[2]) ? 2 : 3;
    float v45 = fminf(m[4], m[5]); int q45 = (v45 == m[4]) ? 4 : 5;
    float v67 = fminf(m[6], m[7]); int q67 = (v67 == m[6]) ? 6 : 7;
    float v03 = fminf(v01, v23);   int q03 = (v03 == v01) ? q01 : q23;
    float v47 = fminf(v45, v67);   int q47 = (v47 == v45) ? q45 : q67;
    float r = fminf(v03, v47);     lq = (r == v03) ? q03 : q47;
    return r;
}

// ---------------------------------------------------------------------------
// Jonker-Volgenant LAP, one wave per batch, zero barriers/LDS in the Dijkstra
// iteration. Bit-exact reference trajectory (structure verified absmax-0 in
// rounds 4/6/8). Round-10 diet: NaN used-sentinel (scan needs no used-mask
// ops; argmin tree NaN-safe), everything else identical to round 8's 600us
// loop incl. early runner-up speculative row prefetch. col = lane*8 + q.
// ---------------------------------------------------------------------------
__global__ __launch_bounds__(64) void lap_kernel(const float* __restrict__ cost,
                                                 int* __restrict__ out) {
    const int b = blockIdx.x;
    const int lane = threadIdx.x;
    const float* C = cost + (size_t)b * NTGT * NPRED;
    const float* Cl = C + lane * 8;       // lane's 8-column slice base

    __shared__ float u0[NTGT + 1];        // row duals (stable during a row-step)
    __shared__ int g2p[NTGT];

    for (int k = lane; k < NTGT + 1; k += 64) u0[k] = 0.f;

    float v[8], minv[8], up[8];
    int p_arr[8], way_arr[8];
#pragma unroll
    for (int q = 0; q < 8; ++q) {
        v[q] = 0.f; up[q] = 0.f; p_arr[q] = 0; way_arr[q] = 0;
    }
    __syncthreads();

    float4 ca = *(const float4*)(Cl);         // prefetch row 0 (row-step i=1)
    float4 cb = *(const float4*)(Cl + 4);
    float4 sa = ca, sb = cb;                  // speculative shadow regs

    for (int i = 1; i <= NTGT; ++i) {
#pragma unroll
        for (int q = 0; q < 8; ++q) minv[q] = BIGF;
        float uI = 0.f;       // u[i] accumulator (virtual col 0), uniform
        float u_i0 = 0.f;     // u of current scan row (row i starts at 0)
        int j0 = 0;
        int j1 = 0;
        int spec_j = 0;       // predicted next winner column (1-based)

        for (int it = 0; it <= NPRED; ++it) {
            float c[8];
            c[0] = ca.x; c[1] = ca.y; c[2] = ca.z; c[3] = ca.w;
            c[4] = cb.x; c[5] = cb.y; c[6] = cb.z; c[7] = cb.w;

            // scan row i0: reduced cost, same float order as reference.
            // used cols have minv == NaN: cur < NaN is false -> inert.
            bool used_b[8];
#pragma unroll
            for (int q = 0; q < 8; ++q) {
                used_b[q] = __builtin_isnan(minv[q]);
                float cur = (c[q] - u_i0) - v[q];
                bool imp = cur < minv[q];
                minv[q] = imp ? cur : minv[q];
                way_arr[q] = imp ? j0 : way_arr[q];
            }

            // primary argmin (exact; tie -> lowest column; NaN drops out)
            int lq;
            float lval = tree8n(minv, lq);
            int   psel = sel8i(p_arr, lq);
            float usel = sel8f(up, lq);
            float wmin = rlf(dpp_min_f32(lval), 63);
            unsigned long long mask = __ballot(lval == wmin);
            int w = (int)__builtin_ctzll(mask);
            int qw  = rl(lq, w);
            int i0n = rl(psel, w);              // p[j1]
            float u_n = rlf(usel, w);           // u0[p[j1]] (start-of-row value)
            float delta = wmin;
            j1 = w * 8 + qw + 1;
            bool done = (i0n == 0);

            if (!done) {
                // demand / hit for the row we must scan next
                if (j1 == spec_j) {
                    ca = sa; cb = sb;           // shadow load already complete
                } else {
                    const float* Crow = Cl + (size_t)(i0n - 1) * NPRED;
                    ca = *(const float4*)(Crow);
                    cb = *(const float4*)(Crow + 4);
                }
                // cheap runner-up speculation for the NEXT iteration, issued
                // before the dual updates (maximum latency cover). Uniform
                // minv shift preserves ordering among old candidates.
                float lv2 = (lane == w) ? QNANF : lval;
                float wm2 = rlf(dpp_min_f32(lv2), 63);
                unsigned long long m2 = __ballot(lv2 == wm2);
                int w2 = (int)__builtin_ctzll(m2);
                int q2 = rl(lq, w2);
                int p2 = rl(psel, w2);
                int sj = w2 * 8 + q2 + 1;
                if (p2 != 0 && sj != spec_j) {
                    const float* Srow = Cl + (size_t)(p2 - 1) * NPRED;
                    sa = *(const float4*)(Srow);
                    sb = *(const float4*)(Srow + 4);
                }
                spec_j = sj;   // if p2==0, a hit implies done (data unused)
            }

            // dual updates (reference order; j1 not yet marked used).
            // x +/- 0.0f is bit-exact; NaN - delta == NaN keeps used cols inert.
            uI += delta;
#pragma unroll
            for (int q = 0; q < 8; ++q) {
                float d0 = used_b[q] ? delta : 0.f;
                v[q]  -= d0;
                up[q] += d0;
                minv[q] -= delta;
            }
            // mark j1 used
            {
                bool lw = (lane == w);
#pragma unroll
                for (int q = 0; q < 8; ++q)
                    minv[q] = (lw && q == qw) ? QNANF : minv[q];
            }

            if (done) break;
            u_i0 = u_n;
            j0 = j1;
        }

        // prefetch next row-step's first scan row (row i, 0-based)
        if (i < NTGT) {
            const float* Crow = Cl + (size_t)i * NPRED;
            ca = *(const float4*)(Crow);
            cb = *(const float4*)(Crow + 4);
        }

        // write back u (pre-augment p): used cols carry u0[p]+deltas in up[]
#pragma unroll
        for (int q = 0; q < 8; ++q) {
            bool usedq = __builtin_isnan(minv[q]);
            if (usedq && p_arr[q] != 0) u0[p_arr[q]] = up[q];
        }
        if (lane == 0) u0[i] = uI;

        // backtrack augmenting path (uniform scalar walk over registers)
        {
            int j = j1;
            for (int s = 0; s <= NPRED; ++s) {
                int ow = (j - 1) >> 3, oq = (j - 1) & 7;
                int wj = rl(sel8i(way_arr, oq), ow);    // way[j]
                int pOfW;
                if (wj == 0) {
                    pOfW = i;                           // p[0] = i (virtual)
                } else {
                    int ow2 = (wj - 1) >> 3, oq2 = (wj - 1) & 7;
                    pOfW = rl(sel8i(p_arr, oq2), ow2);  // old p[way[j]]
                }
#pragma unroll
                for (int q = 0; q < 8; ++q) {
                    bool mine = (lane == ow) && (q == oq);
                    p_arr[q] = mine ? pOfW : p_arr[q];
                }
                if (wj == 0) break;
                j = wj;
            }
        }

        __syncthreads();  // u0 write-back visible before refresh reads
        // refresh up = u0[p[col]] with post-augment p
#pragma unroll
        for (int q = 0; q < 8; ++q) up[q] = u0[p_arr[q]];
    }

    // invert matching: g2p[row] = col (0-based pred index)
#pragma unroll
    for (int q = 0; q < 8; ++q) {
        int r = p_arr[q];
        if (r > 0) g2p[r - 1] = lane * 8 + q;
    }
    __syncthreads();

    // sort by pred index via rank counting (values distinct)
    for (int t = lane; t < NTGT; t += 64) {
        int myv = g2p[t];
        int rank = 0;
        for (int l = 0; l < NTGT; ++l) rank += (g2p[l] < myv) ? 1 : 0;
        out[b * 2 * NTGT + rank] = myv;          // index_i: sorted pred indices
        out[b * 2 * NTGT + NTGT + rank] = t;     // index_j: gt index (argsort)
    }
}

extern "C" void kernel_launch(void* const* d_in, const int* in_sizes, int n_in,
                              void* d_out, int out_size, void* d_ws, size_t ws_size,
                              hipStream_t stream) {
    const float* outputs = (const float*)d_in[0];  // [32, 512, 768]
    const float* targets = (const float*)d_in[1];  // [32, 200, 768]
    int* out = (int*)d_out;                        // [32, 2, 200] int32

    float* cost   = (float*)d_ws;                         // [32][200][512]
    float* no_arr = cost + (size_t)BATCH * NTGT * NPRED;  // [32*512]
    float* nt_arr = no_arr + (size_t)BATCH * NPRED;       // [32*200]

    norms_kernel<<<BATCH * (NPRED + NTGT), 64, 0, stream>>>(outputs, targets,
                                                            no_arr, nt_arr);
    cost_kernel<<<dim3(NPRED / 64, (NTGT + 127) / 128, BATCH), 256, 0, stream>>>(
        outputs, targets, no_arr, nt_arr, cost);
    lap_kernel<<<BATCH, 64, 0, stream>>>(cost, out);
}